// Round 11
// baseline (313.915 us; speedup 1.0000x reference)
//
#include <hip/hip_runtime.h>
#include <hip/hip_fp16.h>

#define NN 100000
#define NE 3200000
#define F 64
#define NR 8
#define NTI 3125               // node tiles = NN/32 (exact: 3125*32 = 100000)
#define NTIP 3128              // padded tile count (mult of 4; extras count 0)
#define SLCAP 1280             // per-tile edge list capacity (mean 1024, +8 sigma)
#define NSB 128                // sort blocks
#define SCH (NE / NSB)         // 25000 edges per sort block
#define CROW 3200              // row stride of counts/base matrices (ints)

typedef _Float16 half8 __attribute__((ext_vector_type(8)));
typedef float f32x4 __attribute__((ext_vector_type(4)));
union U4H8 { uint4 u; half8 h; };

// ---------------- cvt: x fp32 -> fp16 copy ----------------------------------
__global__ __launch_bounds__(256) void cvt_kernel(
    const float* __restrict__ x, __half* __restrict__ xh)
{
    size_t base = ((size_t)blockIdx.x * 256 + threadIdx.x) * 8;
    float4 a = *(const float4*)(x + base);
    float4 b = *(const float4*)(x + base + 4);
    __half2 h0 = __floats2half2_rn(a.x, a.y);
    __half2 h1 = __floats2half2_rn(a.z, a.w);
    __half2 h2 = __floats2half2_rn(b.x, b.y);
    __half2 h3 = __floats2half2_rn(b.z, b.w);
    uint4 o;
    o.x = *(unsigned*)&h0; o.y = *(unsigned*)&h1;
    o.z = *(unsigned*)&h2; o.w = *(unsigned*)&h3;
    *(uint4*)(xh + base) = o;
}

// ---------------- cvtw: {root, weight} -> fp16 TRANSPOSED wt9[s][n][k] ------
__global__ __launch_bounds__(256) void cvtw_kernel(
    const float* __restrict__ weight, const float* __restrict__ root,
    __half* __restrict__ wt9)
{
    int gid = blockIdx.x * 256 + threadIdx.x;   // 0..36863
    int s = gid >> 12;
    int rem = gid & 4095;
    int k = rem >> 6, n = rem & 63;
    const float* src = (s == 0) ? root : (weight + ((size_t)(s - 1) << 12));
    wt9[((size_t)s << 12) + (n << 6) + k] = __float2half_rn(src[(k << 6) + n]);
}

// ---------------- count: per-block private tile histogram (no global atomics)
__global__ __launch_bounds__(512) void count_kernel(
    const int* __restrict__ edst, int* __restrict__ counts)
{
    __shared__ int h[NTIP];
    const int t = threadIdx.x;
    for (int i = t; i < NTIP; i += 512) h[i] = 0;
    __syncthreads();
    const uint4* dv4 = (const uint4*)(edst + blockIdx.x * SCH);
    for (int g = t; g < SCH / 4; g += 512) {
        uint4 dv = dv4[g];
        atomicAdd(&h[dv.x >> 5], 1);
        atomicAdd(&h[dv.y >> 5], 1);
        atomicAdd(&h[dv.z >> 5], 1);
        atomicAdd(&h[dv.w >> 5], 1);
    }
    __syncthreads();
    int* row = counts + blockIdx.x * CROW;
    for (int i = t; i < NTIP; i += 512) row[i] = h[i];   // coalesced, no atomics
}

// ---------------- scanbase: column-reduce + scan + per-block bases ----------
// One block, 1024 threads; thread t owns tiles [4t, 4t+4). Pass A: accumulate
// per-tile totals over the 128 count rows (int4 coalesced). Scan 3128 values
// (wave shfl + cross-wave). Writes tilestart; pass B re-sweeps rows writing
// exact per-(block,tile) bases. Zero global atomics.
__global__ __launch_bounds__(1024) void scanbase_kernel(
    const int* __restrict__ counts, int* __restrict__ tilestart,
    int* __restrict__ base)
{
    __shared__ int wsum[16];
    const int t = threadIdx.x;
    const int lane = t & 63;
    const int wid = t >> 6;
    const bool act = (t < NTIP / 4);        // 782 active threads
    int a0 = 0, a1 = 0, a2 = 0, a3 = 0;
    if (act) {
        for (int b = 0; b < NSB; b++) {
            int4 c = *(const int4*)(counts + b * CROW + (t << 2));
            a0 += c.x; a1 += c.y; a2 += c.z; a3 += c.w;
        }
    }
    const int s = a0 + a1 + a2 + a3;
    int v = s;
#pragma unroll
    for (int off = 1; off < 64; off <<= 1) {
        int u = __shfl_up(v, off);
        if (lane >= off) v += u;
    }
    if (lane == 63) wsum[wid] = v;
    __syncthreads();
    int wo = 0;
#pragma unroll
    for (int w = 0; w < 15; w++) if (w < wid) wo += wsum[w];
    const int tb = wo + v - s;               // exclusive prefix for this thread
    if (act) {
        int r0 = tb, r1 = tb + a0, r2 = r1 + a1, r3 = r2 + a2;
        int4 ts; ts.x = r0; ts.y = r1; ts.z = r2; ts.w = r3;
        *(int4*)(tilestart + (t << 2)) = ts;
        // pass B: running per-block bases
        for (int b = 0; b < NSB; b++) {
            int4 c = *(const int4*)(counts + b * CROW + (t << 2));
            int4 o; o.x = r0; o.y = r1; o.z = r2; o.w = r3;
            *(int4*)(base + b * CROW + (t << 2)) = o;
            r0 += c.x; r1 += c.y; r2 += c.z; r3 += c.w;
        }
    }
    // tilestart[3125] == NE automatically (tiles 3125..3127 have zero counts)
}

// ---------------- scatter: single pass, exact slots, no global atomics ------
__global__ __launch_bounds__(512) void scatter_kernel(
    const int* __restrict__ esrc, const int* __restrict__ edst,
    const int* __restrict__ etyp, const int* __restrict__ base,
    unsigned* __restrict__ packed4)
{
    __shared__ int cur[NTIP];
    const int t = threadIdx.x;
    const int* row = base + blockIdx.x * CROW;
    for (int i = t; i < NTIP; i += 512) cur[i] = row[i];
    __syncthreads();
    const int e0 = blockIdx.x * SCH;
    const uint4* sv4 = (const uint4*)(esrc + e0);
    const uint4* dv4 = (const uint4*)(edst + e0);
    const uint4* rv4 = (const uint4*)(etyp + e0);
    for (int g = t; g < SCH / 4; g += 512) {
        uint4 sv = sv4[g];
        uint4 dv = dv4[g];
        uint4 rv = rv4[g];
#define PUT(S, D, R) { \
        int slot = atomicAdd(&cur[(D) >> 5], 1); \
        packed4[slot] = (S) | (((D) & 31u) << 17) | ((R) << 22); }
        PUT(sv.x, dv.x, rv.x)
        PUT(sv.y, dv.y, rv.y)
        PUT(sv.z, dv.z, rv.z)
        PUT(sv.w, dv.w, rv.w)
#undef PUT
    }
}

// ---------------- fused: sort + fp16 gather + MFMA GEMM (r9 form, proven) ---
__global__ __launch_bounds__(128, 4) void fused_kernel(
    const __half* __restrict__ xh,
    const unsigned* __restrict__ packed4,
    const int* __restrict__ tilestart,
    const __half* __restrict__ wt9,     // [9][64 fout][64 k] fp16 (0 = root)
    const float* __restrict__ bias,
    float* __restrict__ out)
{
    __shared__ __align__(16) char Asb[32 * 128];   // As[node][k] fp16, swizzled, 4 KB
    __shared__ __align__(16) char Wtb[64 * 128];   // Wt[fout][k] fp16, swizzled, 8 KB
    __shared__ int kstart[257];                    // run starts; [256] = total
    __shared__ int slist[SLCAP];                   // 5 KB
    __shared__ int wsum[2];
    int* const kcur = (int*)Asb;         // overlay: dead until staging begins

    const int t = threadIdx.x;
    const int tile = blockIdx.x;
    const int lane = t & 63;
    const int wid = t >> 6;

    const int ebase0 = tilestart[tile];
    const int rc = min(tilestart[tile + 1] - ebase0, SLCAP);

    kstart[t] = 0; kstart[t + 128] = 0;
    __syncthreads();

    // ---- hist by key8 = rel*32 + dstLow5; register-cache the run ----
    unsigned pc[10];
#pragma unroll
    for (int j = 0; j < 10; j++) {
        int i = t + (j << 7);
        if (i < rc) {
            pc[j] = packed4[ebase0 + i];
            atomicAdd(&kstart[pc[j] >> 17], 1);
        }
    }
    __syncthreads();

    // ---- exclusive scan of 256 counts: 2 keys/thread, wave shfl scan ----
    const int a0 = kstart[2 * t], a1 = kstart[2 * t + 1];
    int v = a0 + a1;
#pragma unroll
    for (int off = 1; off < 64; off <<= 1) {
        int u = __shfl_up(v, off);
        if (lane >= off) v += u;
    }
    if (lane == 63) wsum[wid] = v;
    __syncthreads();                       // orders kstart reads vs writes below
    const int wo = wid ? wsum[0] : 0;
    const int incl = wo + v;
    const int ebase = incl - a0 - a1;
    kstart[2 * t]     = ebase;
    kstart[2 * t + 1] = ebase + a0;
    kcur[2 * t]       = ebase;
    kcur[2 * t + 1]   = ebase + a0;
    if (t == 127) kstart[256] = incl;      // total edge count
    __syncthreads();

    // ---- scatter into per-key runs (LDS slist; packed4 from registers) ----
#pragma unroll
    for (int j = 0; j < 10; j++) {
        int i = t + (j << 7);
        if (i < rc) {
            int slot = atomicAdd(&kcur[pc[j] >> 17], 1);
            slist[slot] = (int)(pc[j] & 0x1FFFFu);
        }
    }
    __syncthreads();   // sort frozen; kcur (Asb) dead

    // ---- per-seg: stage Wt -> gather As (wave-private fp16) -> MFMA --------
    const int node0 = tile * 32;
    const int w16 = wid << 4;             // wave's 16-node slice
    const int sn  = w16 + (lane >> 2);    // gather: node within tile 0..31
    const int sq  = lane & 3;             // gather: k-eighth 0..3
    const int kb  = sq << 3;              // halfs [kb,kb+8) and [32+kb,...)
    const unsigned snswz = (unsigned)((sn & 7) << 4);
    char* const awp = Asb + sn * 128;

    // MFMA fragment indices
    const int ml = lane & 15;             // 16-dim: node (A) / fout (B,D)
    const int kg = lane >> 4;             // k-group 0..3
    const int arow = w16 + ml;            // A row = node within tile
    const unsigned aswz = (unsigned)((arow & 7) << 4);
    const unsigned kb0 = (unsigned)(kg << 4);   // kbyte within 64B k-half

    f32x4 acc[4];
#pragma unroll
    for (int nt = 0; nt < 4; nt++)
#pragma unroll
        for (int i = 0; i < 4; i++) acc[nt][i] = 0.f;

    for (int seg = 0; seg < 9; seg++) {
        if (seg) __syncthreads();          // all waves done reading Wtb(seg-1)

        // stage Wt(seg) -> LDS with XOR swizzle (coalesced fp16 source)
        {
            const uint4* __restrict__ wsrc = (const uint4*)(wt9 + ((size_t)seg << 12));
#pragma unroll
            for (int j = 0; j < 4; j++) {
                int c = t + (j << 7);                       // 0..511
                int n = c >> 3;
                unsigned kbyt = (unsigned)((c & 7) << 4);
                *(uint4*)(Wtb + n * 128 + (kbyt ^ (unsigned)((n & 7) << 4))) = wsrc[c];
            }
        }

        if (seg == 0) {
            // root: copy own-row xh straight into As (fp16, swizzled)
            const __half* rowp = xh + (size_t)(node0 + sn) * F + kb;
            uint4 va = *(const uint4*)(rowp);
            uint4 vb = *(const uint4*)(rowp + 32);
            *(uint4*)(awp + (((unsigned)(sq << 4)) ^ snswz)) = va;
            *(uint4*)(awp + ((64u | (unsigned)(sq << 4)) ^ snswz)) = vb;
        } else {
            // mean-gather this wave's 16 nodes for relation seg-1 (fp16 rows)
            const int key = ((seg - 1) << 5) | sn;
            const int beg = kstart[key];
            const int end = kstart[key + 1];   // prefix property: next start
            float4 A0 = make_float4(0.f, 0.f, 0.f, 0.f);
            float4 A1 = A0, B0 = A0, B1 = A0;
            int i = beg;
            for (; i + 4 <= end; i += 4) {     // 4-edge unroll
                const __half* h0 = xh + (size_t)slist[i]     * F + kb;
                const __half* h1 = xh + (size_t)slist[i + 1] * F + kb;
                const __half* h2 = xh + (size_t)slist[i + 2] * F + kb;
                const __half* h3 = xh + (size_t)slist[i + 3] * F + kb;
                uint4 la0 = *(const uint4*)(h0);      uint4 lb0 = *(const uint4*)(h0 + 32);
                uint4 la1 = *(const uint4*)(h1);      uint4 lb1 = *(const uint4*)(h1 + 32);
                uint4 la2 = *(const uint4*)(h2);      uint4 lb2 = *(const uint4*)(h2 + 32);
                uint4 la3 = *(const uint4*)(h3);      uint4 lb3 = *(const uint4*)(h3 + 32);
#define ACC8(v, P, Q) { \
                float2 t0 = __half22float2(*(const __half2*)&(v).x); \
                float2 t1 = __half22float2(*(const __half2*)&(v).y); \
                float2 t2 = __half22float2(*(const __half2*)&(v).z); \
                float2 t3 = __half22float2(*(const __half2*)&(v).w); \
                P.x += t0.x; P.y += t0.y; P.z += t1.x; P.w += t1.y; \
                Q.x += t2.x; Q.y += t2.y; Q.z += t3.x; Q.w += t3.y; }
                ACC8(la0, A0, A1) ACC8(la1, A0, A1) ACC8(la2, A0, A1) ACC8(la3, A0, A1)
                ACC8(lb0, B0, B1) ACC8(lb1, B0, B1) ACC8(lb2, B0, B1) ACC8(lb3, B0, B1)
            }
            for (; i < end; i++) {
                const __half* h0 = xh + (size_t)slist[i] * F + kb;
                uint4 la = *(const uint4*)(h0);
                uint4 lb = *(const uint4*)(h0 + 32);
                ACC8(la, A0, A1)
                ACC8(lb, B0, B1)
            }
#undef ACC8
            const float scl = 1.0f / (float)max(end - beg, 1);
            __half2 p0 = __floats2half2_rn(A0.x * scl, A0.y * scl);
            __half2 p1 = __floats2half2_rn(A0.z * scl, A0.w * scl);
            __half2 p2 = __floats2half2_rn(A1.x * scl, A1.y * scl);
            __half2 p3 = __floats2half2_rn(A1.z * scl, A1.w * scl);
            __half2 q0 = __floats2half2_rn(B0.x * scl, B0.y * scl);
            __half2 q1 = __floats2half2_rn(B0.z * scl, B0.w * scl);
            __half2 q2 = __floats2half2_rn(B1.x * scl, B1.y * scl);
            __half2 q3 = __floats2half2_rn(B1.z * scl, B1.w * scl);
            uint4 pa, pb;
            pa.x = *(unsigned*)&p0; pa.y = *(unsigned*)&p1;
            pa.z = *(unsigned*)&p2; pa.w = *(unsigned*)&p3;
            pb.x = *(unsigned*)&q0; pb.y = *(unsigned*)&q1;
            pb.z = *(unsigned*)&q2; pb.w = *(unsigned*)&q3;
            *(uint4*)(awp + (((unsigned)(sq << 4)) ^ snswz)) = pa;
            *(uint4*)(awp + ((64u | (unsigned)(sq << 4)) ^ snswz)) = pb;
        }
        __syncthreads();                   // Wtb(seg) staged & visible

        // MFMA GEMM: D[16 node x 64 fout] += A[16x64] * W[64x64]
        U4H8 fa0, fa1;
        fa0.u = *(const uint4*)(Asb + arow * 128 + (kb0 ^ aswz));
        fa1.u = *(const uint4*)(Asb + arow * 128 + ((64u | kb0) ^ aswz));
#pragma unroll
        for (int nt = 0; nt < 4; nt++) {
            int wrow = (nt << 4) + ml;
            unsigned wswz = (unsigned)((wrow & 7) << 4);
            U4H8 fb0, fb1;
            fb0.u = *(const uint4*)(Wtb + wrow * 128 + (kb0 ^ wswz));
            fb1.u = *(const uint4*)(Wtb + wrow * 128 + ((64u | kb0) ^ wswz));
            acc[nt] = __builtin_amdgcn_mfma_f32_16x16x32_f16(fa0.h, fb0.h, acc[nt], 0, 0, 0);
            acc[nt] = __builtin_amdgcn_mfma_f32_16x16x32_f16(fa1.h, fb1.h, acc[nt], 0, 0, 0);
        }
    }

    // epilogue: + bias; D mapping col=lane&15, row=(lane>>4)*4+i (verified)
#pragma unroll
    for (int nt = 0; nt < 4; nt++) {
        float bb = bias[(nt << 4) + ml];
#pragma unroll
        for (int i = 0; i < 4; i++) {
            int node = node0 + w16 + (kg << 2) + i;
            out[(size_t)node * F + (nt << 4) + ml] = acc[nt][i] + bb;
        }
    }
}

extern "C" void kernel_launch(void* const* d_in, const int* in_sizes, int n_in,
                              void* d_out, int out_size, void* d_ws, size_t ws_size,
                              hipStream_t stream) {
    const float* x    = (const float*)d_in[0];
    const int*   ei   = (const int*)d_in[1];
    const int*   et   = (const int*)d_in[2];
    const float* wgt  = (const float*)d_in[3];
    const float* root = (const float*)d_in[4];
    const float* bias = (const float*)d_in[5];
    float*       out  = (float*)d_out;

    char* ws = (char*)d_ws;
    int*      tilestart = (int*)ws;                              // [3128]  16 KB slot
    int*      counts    = (int*)(ws + 16384);                    // [128][3200] 1.6 MB
    int*      base      = (int*)(ws + 16384 + (size_t)NSB * CROW * 4);   // 1.6 MB
    unsigned* packed4   = (unsigned*)(ws + 16384 + 2 * (size_t)NSB * CROW * 4); // 12.8 MB
    __half*   xh        = (__half*)((char*)packed4 + (size_t)NE * 4);    // 12.8 MB
    __half*   wt9       = xh + (size_t)NN * F;                           // 72 KB

    cvt_kernel<<<NN * F / (256 * 8), 256, 0, stream>>>(x, xh);
    cvtw_kernel<<<144, 256, 0, stream>>>(wgt, root, wt9);
    count_kernel<<<NSB, 512, 0, stream>>>(ei + NE, counts);
    scanbase_kernel<<<1, 1024, 0, stream>>>(counts, tilestart, base);
    scatter_kernel<<<NSB, 512, 0, stream>>>(ei, ei + NE, et, base, packed4);
    fused_kernel<<<NTI, 128, 0, stream>>>(xh, packed4, tilestart, wt9, bias, out);
}

// Round 12
// 253.572 us; speedup vs baseline: 1.2380x; 1.2380x over previous
//
#include <hip/hip_runtime.h>
#include <hip/hip_fp16.h>

#define NN 100000
#define NE 3200000
#define F 64
#define NR 8
#define NTI 3125               // node tiles = NN/32 (exact: 3125*32 = 100000)
#define NTIP 3128              // padded tile count (mult of 4; extras count 0)
#define SLCAP 1280             // per-tile edge list capacity (mean 1024, +8 sigma)
#define NSB 250                // sort blocks (full-chip grid; 12800 edges each)
#define SCH (NE / NSB)         // 12800 edges per sort block
#define NSBP 256               // padded sort-block count (tile-major row length)
#define CROWB 3200             // base row stride (block-major), ints

typedef _Float16 half8 __attribute__((ext_vector_type(8)));
typedef float f32x4 __attribute__((ext_vector_type(4)));
union U4H8 { uint4 u; half8 h; };

// ---------------- cvt: x fp32 -> fp16 copy ----------------------------------
__global__ __launch_bounds__(256) void cvt_kernel(
    const float* __restrict__ x, __half* __restrict__ xh)
{
    size_t base = ((size_t)blockIdx.x * 256 + threadIdx.x) * 8;
    float4 a = *(const float4*)(x + base);
    float4 b = *(const float4*)(x + base + 4);
    __half2 h0 = __floats2half2_rn(a.x, a.y);
    __half2 h1 = __floats2half2_rn(a.z, a.w);
    __half2 h2 = __floats2half2_rn(b.x, b.y);
    __half2 h3 = __floats2half2_rn(b.z, b.w);
    uint4 o;
    o.x = *(unsigned*)&h0; o.y = *(unsigned*)&h1;
    o.z = *(unsigned*)&h2; o.w = *(unsigned*)&h3;
    *(uint4*)(xh + base) = o;
}

// ---------------- cvtw: {root, weight} -> fp16 TRANSPOSED wt9[s][n][k] ------
__global__ __launch_bounds__(256) void cvtw_kernel(
    const float* __restrict__ weight, const float* __restrict__ root,
    __half* __restrict__ wt9)
{
    int gid = blockIdx.x * 256 + threadIdx.x;   // 0..36863
    int s = gid >> 12;
    int rem = gid & 4095;
    int k = rem >> 6, n = rem & 63;
    const float* src = (s == 0) ? root : (weight + ((size_t)(s - 1) << 12));
    wt9[((size_t)s << 12) + (n << 6) + k] = __float2half_rn(src[(k << 6) + n]);
}

// ---------------- count: per-block tile histogram, TILE-MAJOR output --------
__global__ __launch_bounds__(512) void count_kernel(
    const int* __restrict__ edst, int* __restrict__ counts)
{
    __shared__ int h[NTIP];
    const int t = threadIdx.x;
    for (int i = t; i < NTIP; i += 512) h[i] = 0;
    __syncthreads();
    const uint4* dv4 = (const uint4*)(edst + blockIdx.x * SCH);
    for (int g = t; g < SCH / 4; g += 512) {
        uint4 dv = dv4[g];
        atomicAdd(&h[dv.x >> 5], 1);
        atomicAdd(&h[dv.y >> 5], 1);
        atomicAdd(&h[dv.z >> 5], 1);
        atomicAdd(&h[dv.w >> 5], 1);
    }
    __syncthreads();
    for (int i = t; i < NTIP; i += 512)
        counts[i * NSBP + blockIdx.x] = h[i];   // tile-major for scanA
}

// ---------------- scanA: one WAVE per tile — scan 250 block-counts ----------
// Reads the tile's 256-int row coalesced (1 KB), 64-lane shfl scan, writes
// block-major exclusive bases + the tile total. Fully parallel (782 blocks).
__global__ __launch_bounds__(256) void scanA_kernel(
    const int* __restrict__ counts, int* __restrict__ base,
    int* __restrict__ tiletot)
{
    const int t = threadIdx.x;
    const int lane = t & 63;
    const int T = blockIdx.x * 4 + (t >> 6);     // 782*4 = 3128 tiles exact
    int4 c = *(const int4*)(counts + T * NSBP + (lane << 2));
    const int b0 = lane << 2;
    int c0 = (b0 + 0 < NSB) ? c.x : 0;           // mask pad columns (unwritten)
    int c1 = (b0 + 1 < NSB) ? c.y : 0;
    int c2 = (b0 + 2 < NSB) ? c.z : 0;
    int c3 = (b0 + 3 < NSB) ? c.w : 0;
    const int s = c0 + c1 + c2 + c3;
    int v = s;
#pragma unroll
    for (int off = 1; off < 64; off <<= 1) {
        int u = __shfl_up(v, off);
        if (lane >= off) v += u;
    }
    const int e = v - s;                          // exclusive across lanes
    if (b0 + 0 < NSB) base[(b0 + 0) * CROWB + T] = e;
    if (b0 + 1 < NSB) base[(b0 + 1) * CROWB + T] = e + c0;
    if (b0 + 2 < NSB) base[(b0 + 2) * CROWB + T] = e + c0 + c1;
    if (b0 + 3 < NSB) base[(b0 + 3) * CROWB + T] = e + c0 + c1 + c2;
    int tot = __shfl(v, 63);
    if (lane == 0) tiletot[T] = tot;
}

// ---------------- scanT: scan 3128 tile totals -> tilestart (tiny) ----------
__global__ __launch_bounds__(1024) void scanT_kernel(
    const int* __restrict__ tiletot, int* __restrict__ tilestart)
{
    __shared__ int wsum[16];
    const int t = threadIdx.x;
    const int lane = t & 63;
    const int wid = t >> 6;
    const bool act = (t < NTIP / 4);             // 782 active threads
    int4 c = make_int4(0, 0, 0, 0);
    if (act) c = *(const int4*)(tiletot + (t << 2));
    const int s = c.x + c.y + c.z + c.w;
    int v = s;
#pragma unroll
    for (int off = 1; off < 64; off <<= 1) {
        int u = __shfl_up(v, off);
        if (lane >= off) v += u;
    }
    if (lane == 63) wsum[wid] = v;
    __syncthreads();
    int wo = 0;
#pragma unroll
    for (int w = 0; w < 15; w++) if (w < wid) wo += wsum[w];
    const int tb = wo + v - s;
    if (act) {
        int4 ts;
        ts.x = tb; ts.y = tb + c.x; ts.z = ts.y + c.y; ts.w = ts.z + c.z;
        *(int4*)(tilestart + (t << 2)) = ts;
    }
    // tilestart[3125] == NE automatically (tiles 3125..3127 count 0)
}

// ---------------- scatter: exact slots, LDS cursors, full-chip grid ---------
__global__ __launch_bounds__(512) void scatter_kernel(
    const int* __restrict__ esrc, const int* __restrict__ edst,
    const int* __restrict__ etyp, const int* __restrict__ base,
    const int* __restrict__ tilestart, unsigned* __restrict__ packed4)
{
    __shared__ int cur[NTIP];
    const int t = threadIdx.x;
    const int* row = base + blockIdx.x * CROWB;
    for (int i = t; i < NTIP; i += 512) cur[i] = row[i] + tilestart[i];
    __syncthreads();
    const int e0 = blockIdx.x * SCH;
    const uint4* sv4 = (const uint4*)(esrc + e0);
    const uint4* dv4 = (const uint4*)(edst + e0);
    const uint4* rv4 = (const uint4*)(etyp + e0);
    for (int g = t; g < SCH / 4; g += 512) {
        uint4 sv = sv4[g];
        uint4 dv = dv4[g];
        uint4 rv = rv4[g];
#define PUT(S, D, R) { \
        int slot = atomicAdd(&cur[(D) >> 5], 1); \
        packed4[slot] = (S) | (((D) & 31u) << 17) | ((R) << 22); }
        PUT(sv.x, dv.x, rv.x)
        PUT(sv.y, dv.y, rv.y)
        PUT(sv.z, dv.z, rv.z)
        PUT(sv.w, dv.w, rv.w)
#undef PUT
    }
}

// ---------------- fused: sort + fp16 gather + MFMA GEMM (r11 form, proven) --
__global__ __launch_bounds__(128, 4) void fused_kernel(
    const __half* __restrict__ xh,
    const unsigned* __restrict__ packed4,
    const int* __restrict__ tilestart,
    const __half* __restrict__ wt9,     // [9][64 fout][64 k] fp16 (0 = root)
    const float* __restrict__ bias,
    float* __restrict__ out)
{
    __shared__ __align__(16) char Asb[32 * 128];   // As[node][k] fp16, swizzled, 4 KB
    __shared__ __align__(16) char Wtb[64 * 128];   // Wt[fout][k] fp16, swizzled, 8 KB
    __shared__ int kstart[257];                    // run starts; [256] = total
    __shared__ int slist[SLCAP];                   // 5 KB
    __shared__ int wsum[2];
    int* const kcur = (int*)Asb;         // overlay: dead until staging begins

    const int t = threadIdx.x;
    const int tile = blockIdx.x;
    const int lane = t & 63;
    const int wid = t >> 6;

    const int ebase0 = tilestart[tile];
    const int rc = min(tilestart[tile + 1] - ebase0, SLCAP);

    kstart[t] = 0; kstart[t + 128] = 0;
    __syncthreads();

    // ---- hist by key8 = rel*32 + dstLow5; register-cache the run ----
    unsigned pc[10];
#pragma unroll
    for (int j = 0; j < 10; j++) {
        int i = t + (j << 7);
        if (i < rc) {
            pc[j] = packed4[ebase0 + i];
            atomicAdd(&kstart[pc[j] >> 17], 1);
        }
    }
    __syncthreads();

    // ---- exclusive scan of 256 counts: 2 keys/thread, wave shfl scan ----
    const int a0 = kstart[2 * t], a1 = kstart[2 * t + 1];
    int v = a0 + a1;
#pragma unroll
    for (int off = 1; off < 64; off <<= 1) {
        int u = __shfl_up(v, off);
        if (lane >= off) v += u;
    }
    if (lane == 63) wsum[wid] = v;
    __syncthreads();                       // orders kstart reads vs writes below
    const int wo = wid ? wsum[0] : 0;
    const int incl = wo + v;
    const int ebase = incl - a0 - a1;
    kstart[2 * t]     = ebase;
    kstart[2 * t + 1] = ebase + a0;
    kcur[2 * t]       = ebase;
    kcur[2 * t + 1]   = ebase + a0;
    if (t == 127) kstart[256] = incl;      // total edge count
    __syncthreads();

    // ---- scatter into per-key runs (LDS slist; packed4 from registers) ----
#pragma unroll
    for (int j = 0; j < 10; j++) {
        int i = t + (j << 7);
        if (i < rc) {
            int slot = atomicAdd(&kcur[pc[j] >> 17], 1);
            slist[slot] = (int)(pc[j] & 0x1FFFFu);
        }
    }
    __syncthreads();   // sort frozen; kcur (Asb) dead

    // ---- per-seg: stage Wt -> gather As (wave-private fp16) -> MFMA --------
    const int node0 = tile * 32;
    const int w16 = wid << 4;             // wave's 16-node slice
    const int sn  = w16 + (lane >> 2);    // gather: node within tile 0..31
    const int sq  = lane & 3;             // gather: k-eighth 0..3
    const int kb  = sq << 3;              // halfs [kb,kb+8) and [32+kb,...)
    const unsigned snswz = (unsigned)((sn & 7) << 4);
    char* const awp = Asb + sn * 128;

    // MFMA fragment indices
    const int ml = lane & 15;             // 16-dim: node (A) / fout (B,D)
    const int kg = lane >> 4;             // k-group 0..3
    const int arow = w16 + ml;            // A row = node within tile
    const unsigned aswz = (unsigned)((arow & 7) << 4);
    const unsigned kb0 = (unsigned)(kg << 4);   // kbyte within 64B k-half

    f32x4 acc[4];
#pragma unroll
    for (int nt = 0; nt < 4; nt++)
#pragma unroll
        for (int i = 0; i < 4; i++) acc[nt][i] = 0.f;

    for (int seg = 0; seg < 9; seg++) {
        if (seg) __syncthreads();          // all waves done reading Wtb(seg-1)

        // stage Wt(seg) -> LDS with XOR swizzle (coalesced fp16 source)
        {
            const uint4* __restrict__ wsrc = (const uint4*)(wt9 + ((size_t)seg << 12));
#pragma unroll
            for (int j = 0; j < 4; j++) {
                int c = t + (j << 7);                       // 0..511
                int n = c >> 3;
                unsigned kbyt = (unsigned)((c & 7) << 4);
                *(uint4*)(Wtb + n * 128 + (kbyt ^ (unsigned)((n & 7) << 4))) = wsrc[c];
            }
        }

        if (seg == 0) {
            // root: copy own-row xh straight into As (fp16, swizzled)
            const __half* rowp = xh + (size_t)(node0 + sn) * F + kb;
            uint4 va = *(const uint4*)(rowp);
            uint4 vb = *(const uint4*)(rowp + 32);
            *(uint4*)(awp + (((unsigned)(sq << 4)) ^ snswz)) = va;
            *(uint4*)(awp + ((64u | (unsigned)(sq << 4)) ^ snswz)) = vb;
        } else {
            // mean-gather this wave's 16 nodes for relation seg-1 (fp16 rows)
            const int key = ((seg - 1) << 5) | sn;
            const int beg = kstart[key];
            const int end = kstart[key + 1];   // prefix property: next start
            float4 A0 = make_float4(0.f, 0.f, 0.f, 0.f);
            float4 A1 = A0, B0 = A0, B1 = A0;
            int i = beg;
            for (; i + 4 <= end; i += 4) {     // 4-edge unroll
                const __half* h0 = xh + (size_t)slist[i]     * F + kb;
                const __half* h1 = xh + (size_t)slist[i + 1] * F + kb;
                const __half* h2 = xh + (size_t)slist[i + 2] * F + kb;
                const __half* h3 = xh + (size_t)slist[i + 3] * F + kb;
                uint4 la0 = *(const uint4*)(h0);      uint4 lb0 = *(const uint4*)(h0 + 32);
                uint4 la1 = *(const uint4*)(h1);      uint4 lb1 = *(const uint4*)(h1 + 32);
                uint4 la2 = *(const uint4*)(h2);      uint4 lb2 = *(const uint4*)(h2 + 32);
                uint4 la3 = *(const uint4*)(h3);      uint4 lb3 = *(const uint4*)(h3 + 32);
#define ACC8(v, P, Q) { \
                float2 t0 = __half22float2(*(const __half2*)&(v).x); \
                float2 t1 = __half22float2(*(const __half2*)&(v).y); \
                float2 t2 = __half22float2(*(const __half2*)&(v).z); \
                float2 t3 = __half22float2(*(const __half2*)&(v).w); \
                P.x += t0.x; P.y += t0.y; P.z += t1.x; P.w += t1.y; \
                Q.x += t2.x; Q.y += t2.y; Q.z += t3.x; Q.w += t3.y; }
                ACC8(la0, A0, A1) ACC8(la1, A0, A1) ACC8(la2, A0, A1) ACC8(la3, A0, A1)
                ACC8(lb0, B0, B1) ACC8(lb1, B0, B1) ACC8(lb2, B0, B1) ACC8(lb3, B0, B1)
            }
            for (; i < end; i++) {
                const __half* h0 = xh + (size_t)slist[i] * F + kb;
                uint4 la = *(const uint4*)(h0);
                uint4 lb = *(const uint4*)(h0 + 32);
                ACC8(la, A0, A1)
                ACC8(lb, B0, B1)
            }
#undef ACC8
            const float scl = 1.0f / (float)max(end - beg, 1);
            __half2 p0 = __floats2half2_rn(A0.x * scl, A0.y * scl);
            __half2 p1 = __floats2half2_rn(A0.z * scl, A0.w * scl);
            __half2 p2 = __floats2half2_rn(A1.x * scl, A1.y * scl);
            __half2 p3 = __floats2half2_rn(A1.z * scl, A1.w * scl);
            __half2 q0 = __floats2half2_rn(B0.x * scl, B0.y * scl);
            __half2 q1 = __floats2half2_rn(B0.z * scl, B0.w * scl);
            __half2 q2 = __floats2half2_rn(B1.x * scl, B1.y * scl);
            __half2 q3 = __floats2half2_rn(B1.z * scl, B1.w * scl);
            uint4 pa, pb;
            pa.x = *(unsigned*)&p0; pa.y = *(unsigned*)&p1;
            pa.z = *(unsigned*)&p2; pa.w = *(unsigned*)&p3;
            pb.x = *(unsigned*)&q0; pb.y = *(unsigned*)&q1;
            pb.z = *(unsigned*)&q2; pb.w = *(unsigned*)&q3;
            *(uint4*)(awp + (((unsigned)(sq << 4)) ^ snswz)) = pa;
            *(uint4*)(awp + ((64u | (unsigned)(sq << 4)) ^ snswz)) = pb;
        }
        __syncthreads();                   // Wtb(seg) staged & visible

        // MFMA GEMM: D[16 node x 64 fout] += A[16x64] * W[64x64]
        U4H8 fa0, fa1;
        fa0.u = *(const uint4*)(Asb + arow * 128 + (kb0 ^ aswz));
        fa1.u = *(const uint4*)(Asb + arow * 128 + ((64u | kb0) ^ aswz));
#pragma unroll
        for (int nt = 0; nt < 4; nt++) {
            int wrow = (nt << 4) + ml;
            unsigned wswz = (unsigned)((wrow & 7) << 4);
            U4H8 fb0, fb1;
            fb0.u = *(const uint4*)(Wtb + wrow * 128 + (kb0 ^ wswz));
            fb1.u = *(const uint4*)(Wtb + wrow * 128 + ((64u | kb0) ^ wswz));
            acc[nt] = __builtin_amdgcn_mfma_f32_16x16x32_f16(fa0.h, fb0.h, acc[nt], 0, 0, 0);
            acc[nt] = __builtin_amdgcn_mfma_f32_16x16x32_f16(fa1.h, fb1.h, acc[nt], 0, 0, 0);
        }
    }

    // epilogue: + bias; D mapping col=lane&15, row=(lane>>4)*4+i (verified)
#pragma unroll
    for (int nt = 0; nt < 4; nt++) {
        float bb = bias[(nt << 4) + ml];
#pragma unroll
        for (int i = 0; i < 4; i++) {
            int node = node0 + w16 + (kg << 2) + i;
            out[(size_t)node * F + (nt << 4) + ml] = acc[nt][i] + bb;
        }
    }
}

extern "C" void kernel_launch(void* const* d_in, const int* in_sizes, int n_in,
                              void* d_out, int out_size, void* d_ws, size_t ws_size,
                              hipStream_t stream) {
    const float* x    = (const float*)d_in[0];
    const int*   ei   = (const int*)d_in[1];
    const int*   et   = (const int*)d_in[2];
    const float* wgt  = (const float*)d_in[3];
    const float* root = (const float*)d_in[4];
    const float* bias = (const float*)d_in[5];
    float*       out  = (float*)d_out;

    char* ws = (char*)d_ws;
    int*      tilestart = (int*)ws;                                   // 16 KB slot
    int*      tiletot   = (int*)(ws + 16384);                         // 16 KB slot
    int*      counts    = (int*)(ws + 32768);                         // [3128][256] 3.2 MB
    int*      base      = counts + (size_t)NTIP * NSBP;               // [256][3200] 3.3 MB
    unsigned* packed4   = (unsigned*)(base + (size_t)NSBP * CROWB);   // 12.8 MB
    __half*   xh        = (__half*)(packed4 + (size_t)NE);            // 12.8 MB
    __half*   wt9       = xh + (size_t)NN * F;                        // 72 KB

    cvt_kernel<<<NN * F / (256 * 8), 256, 0, stream>>>(x, xh);
    cvtw_kernel<<<144, 256, 0, stream>>>(wgt, root, wt9);
    count_kernel<<<NSB, 512, 0, stream>>>(ei + NE, counts);
    scanA_kernel<<<NTIP / 4, 256, 0, stream>>>(counts, base, tiletot);
    scanT_kernel<<<1, 1024, 0, stream>>>(tiletot, tilestart);
    scatter_kernel<<<NSB, 512, 0, stream>>>(ei, ei + NE, et, base, tilestart, packed4);
    fused_kernel<<<NTI, 128, 0, stream>>>(xh, packed4, tilestart, wt9, bias, out);
}